// Round 6
// baseline (57.276 us; speedup 1.0000x reference)
//
#include <hip/hip_runtime.h>
#include <hip/hip_bf16.h>

#define TT 8000
#define BB 64
#define NBINS 24
#define CAP 256
#define NT 512
#define NS 16    // stripes: t = tid + s*512
#define NHB 512  // histogram bins

// =================== K1: energy = mean(mel, axis=-1), LDS-staged coalesced ====================
__global__ __launch_bounds__(256) void k_energy(const float* __restrict__ mel,
                                                double* __restrict__ e_bt){
  __shared__ float sm[5120];
  const int blk = blockIdx.x, tid = threadIdx.x;
  const float4* g = (const float4*)(mel + (size_t)blk * 5120);
  float4* s4 = (float4*)sm;
  #pragma unroll
  for (int j = 0; j < 5; ++j) s4[tid + j * 256] = g[tid + j * 256];
  __syncthreads();
  const float* p = sm + tid * 20;
  double s = 0.0;
  #pragma unroll
  for (int j = 0; j < 20; ++j) s += (double)p[j];
  s += __shfl_xor(s, 1, 64);
  s += __shfl_xor(s, 2, 64);
  if ((tid & 3) == 0) e_bt[(size_t)blk * 64 + (tid >> 2)] = s / 80.0;
}

// ---- rare-path exact bisection select (round-4/5 proven), writes scD[OUTLO], scD[OUTLO+1] ----
#define FALLBACK(VALS, RNK, OUTLO, MAXV, CBASE)                                  \
  {                                                                              \
    double lo_ = -0.5, hi_ = (MAXV);                                             \
    int cl_ = 0, ch_ = 8000;                                                     \
    for (;;){                                                                    \
      if (ch_ - cl_ <= CAP){                                                     \
        if (tid == 0) redI[0] = 0;                                               \
        __syncthreads();                                                         \
        _Pragma("unroll")                                                        \
        for (int s = 0; s < NS; ++s){                                            \
          int t = tid + (s << 9);                                                \
          if (t < TT){ double v = VALS[s];                                       \
            if (v > lo_ && v <= hi_){ int ix = atomicAdd(&redI[0], 1);           \
              if (ix < CAP) cand[(CBASE) + ix] = v; } }                          \
        }                                                                        \
        __syncthreads();                                                         \
        int n = redI[0]; if (n > CAP) n = CAP;                                   \
        int tgt = (RNK) - cl_;                                                   \
        if (tid < n){                                                            \
          double mv = cand[(CBASE) + tid];                                       \
          int rk = 0;                                                            \
          for (int j = 0; j < n; ++j){ double cj = cand[(CBASE) + j];            \
            rk += (cj < mv || (cj == mv && j < tid)) ? 1 : 0; }                  \
          if (rk == tgt)     scD[OUTLO] = mv;                                    \
          if (rk == tgt + 1) scD[(OUTLO) + 1] = mv;                              \
        }                                                                        \
        __syncthreads();                                                         \
        break;                                                                   \
      }                                                                          \
      double mid_ = 0.5 * (lo_ + hi_);                                           \
      if (!(mid_ > lo_ && mid_ < hi_)){                                          \
        if (tid == 0){ scD[OUTLO] = hi_; scD[(OUTLO) + 1] = hi_; }               \
        __syncthreads();                                                         \
        break;                                                                   \
      }                                                                          \
      int c_ = 0;                                                                \
      _Pragma("unroll")                                                          \
      for (int s = 0; s < NS; ++s){                                              \
        int t = tid + (s << 9);                                                  \
        if (t < TT && VALS[s] <= mid_) c_++;                                     \
      }                                                                          \
      _Pragma("unroll")                                                          \
      for (int o = 32; o; o >>= 1) c_ += __shfl_down(c_, o, 64);                 \
      if (lane == 0) redI[wid] = c_;                                             \
      __syncthreads();                                                           \
      if (tid == 0){ int a2 = 0; for (int i = 0; i < 8; ++i) a2 += redI[i]; scI[5] = a2; } \
      __syncthreads();                                                           \
      int ct_ = scI[5];                                                          \
      if (ct_ <= (RNK)){ lo_ = mid_; cl_ = ct_; }                                \
      else if (ct_ >= (RNK) + 2){ hi_ = mid_; ch_ = ct_; }                       \
      else {                                                                     \
        double mx_ = -1.0, mn_ = 1e300;                                          \
        _Pragma("unroll")                                                        \
        for (int s = 0; s < NS; ++s){                                            \
          int t = tid + (s << 9);                                                \
          if (t < TT){ double v = VALS[s];                                       \
            if (v <= mid_){ if (v > mx_) mx_ = v; } else { if (v < mn_) mn_ = v; } } \
        }                                                                        \
        _Pragma("unroll")                                                        \
        for (int o = 32; o; o >>= 1){ double x = __shfl_down(mx_, o, 64); if (x > mx_) mx_ = x; } \
        if (lane == 0) redD[wid] = mx_;                                          \
        __syncthreads();                                                         \
        if (tid == 0){ double a2 = redD[0]; for (int i = 1; i < 8; ++i) if (redD[i] > a2) a2 = redD[i]; scD[OUTLO] = a2; } \
        __syncthreads();                                                         \
        _Pragma("unroll")                                                        \
        for (int o = 32; o; o >>= 1){ double x = __shfl_down(mn_, o, 64); if (x < mn_) mn_ = x; } \
        if (lane == 0) redD[wid] = mn_;                                          \
        __syncthreads();                                                         \
        if (tid == 0){ double a2 = redD[0]; for (int i = 1; i < 8; ++i) if (redD[i] < a2) a2 = redD[i]; scD[(OUTLO) + 1] = a2; } \
        __syncthreads();                                                         \
        break;                                                                   \
      }                                                                          \
    }                                                                            \
  }

// =================== K2: one block per row, everything fused, 8 waves ====================
__global__ __launch_bounds__(NT) void k_row(const double* __restrict__ e_all,
                                            float* __restrict__ out){
  __shared__ double e_s[TT];                          // 64000 B
  __shared__ double delta_s[TT];                      // 64000 B
  __shared__ __align__(16) unsigned short runs[TT];   // 16000 B (aliased as hists early)
  __shared__ unsigned char flags[TT];                 //  8000 B
  __shared__ double cand[2 * CAP];                    //  4096 B  [0:CAP) D, [CAP:2CAP) B
  __shared__ double redD[32];
  __shared__ int    redI[8];
  __shared__ double scD[12];  // 0 mu 1 sd 2 dthr 3 bthr 4 dlo 5 dhi 6 blo 7 bhi 8 tf 9 maxd 10 maxb
  __shared__ int    scI[16];  // 0-3 D locate | 4 candND | 5 fb-count | 8-11 B locate | 12 candNB
  __shared__ int    wTD[8], wOD[8], wTB[8], wOB[8], wT[8], wO[8];
  __shared__ int    cnt5[5];
  int* histD = (int*)runs;        // 2048 B
  int* histB = histD + NHB;       // 2048 B  (runs not used until after quantiles)

  const int b = blockIdx.x, tid = threadIdx.x;
  const int lane = tid & 63, wid = tid >> 6;
  const double* eg = e_all + (size_t)b * TT;

  if (tid < 5) cnt5[tid] = 0;
  if (tid < 16) scI[tid] = 0;
  histD[tid] = 0; histB[tid] = 0;                     // tid<512 covers both fully

  double ev[NS], dv[NS], bv[NS];
  // ---- load e (striped: lane-consecutive) ----
  #pragma unroll
  for (int s = 0; s < NS; ++s){
    int t = tid + (s << 9);
    double e = (t < TT) ? eg[t] : 0.0;
    ev[s] = e;
    if (t < TT) e_s[t] = e;
  }
  __syncthreads();                                    // B1
  // ---- delta ----
  #pragma unroll
  for (int s = 0; s < NS; ++s){
    int t = tid + (s << 9);
    double d = 0.0;
    if (t > 0 && t < TT) d = fabs(e_s[t] - e_s[t-1]);
    dv[s] = d;
    if (t < TT) delta_s[t] = d;
  }
  __syncthreads();                                    // B2
  // ---- bs (window-7 mean) ----
  #pragma unroll
  for (int s = 0; s < NS; ++s){
    int t = tid + (s << 9);
    double sum = 0.0;
    if (t < TT){
      int j0 = t - 3; if (j0 < 0) j0 = 0;
      int j1 = t + 3; if (j1 > TT-1) j1 = TT-1;
      for (int j = j0; j <= j1; ++j) sum += delta_s[j];
    }
    bv[s] = sum / 7.0;
  }
  // ---- fused reduce: sum(e), sum(e^2), max(dv), max(bv) ----
  {
    double se = 0.0, s2 = 0.0, md = 0.0, mb = 0.0;
    #pragma unroll
    for (int s = 0; s < NS; ++s){
      se += ev[s]; s2 += ev[s] * ev[s];
      if (dv[s] > md) md = dv[s];
      if (bv[s] > mb) mb = bv[s];
    }
    #pragma unroll
    for (int o = 32; o; o >>= 1){
      se += __shfl_down(se, o, 64);
      s2 += __shfl_down(s2, o, 64);
      double x = __shfl_down(md, o, 64); if (x > md) md = x;
      x = __shfl_down(mb, o, 64); if (x > mb) mb = x;
    }
    if (lane == 0){ redD[wid] = se; redD[8+wid] = s2; redD[16+wid] = md; redD[24+wid] = mb; }
  }
  __syncthreads();                                    // B3
  if (tid < 64){
    double a = (lane < 8) ? redD[lane]      : 0.0;
    double q = (lane < 8) ? redD[8 + lane]  : 0.0;
    double c = (lane < 8) ? redD[16 + lane] : 0.0;
    double d = (lane < 8) ? redD[24 + lane] : 0.0;
    #pragma unroll
    for (int o = 4; o; o >>= 1){
      a += __shfl_down(a, o, 64);
      q += __shfl_down(q, o, 64);
      double x = __shfl_down(c, o, 64); if (x > c) c = x;
      x = __shfl_down(d, o, 64); if (x > d) d = x;
    }
    if (lane == 0){
      double mu0 = a / 8000.0;
      double var = (q - a * a / 8000.0) / 7999.0;
      if (var < 0.0) var = 0.0;
      double sd0 = sqrt(var); if (sd0 < 1e-6) sd0 = 1e-6;
      scD[0] = mu0; scD[1] = sd0; scD[9] = c; scD[10] = d;
    }
  }
  __syncthreads();                                    // B4
  const double mu = scD[0], sd = scD[1];
  const double maxd = scD[9], maxb = scD[10];
  const bool doD = (maxd > 0.0), doB = (maxb > 0.0);
  const double sclD = doD ? (double)NHB / maxd : 0.0;
  const double sclB = doB ? (double)NHB / maxb : 0.0;
  // ---- joint histogram fill ----
  #pragma unroll
  for (int s = 0; s < NS; ++s){
    int t = tid + (s << 9);
    if (t < TT){
      if (doD){ int bi = (int)(dv[s] * sclD); if (bi > NHB-1) bi = NHB-1; atomicAdd(&histD[bi], 1); }
      if (doB){ int bi = (int)(bv[s] * sclB); if (bi > NHB-1) bi = NHB-1; atomicAdd(&histB[bi], 1); }
    }
  }
  __syncthreads();                                    // B5
  // ---- joint scan of both 512-bin hists ----
  const int hD = histD[tid], hB = histB[tid];
  int incD = hD, incB = hB;
  #pragma unroll
  for (int o = 1; o < 64; o <<= 1){
    int x = __shfl_up(incD, o, 64); if (lane >= o) incD += x;
    x = __shfl_up(incB, o, 64); if (lane >= o) incB += x;
  }
  if (lane == 63){ wTD[wid] = incD; wTB[wid] = incB; }
  __syncthreads();                                    // B6
  if (tid < 64){
    int vD = (lane < 8) ? wTD[lane] : 0;
    int vB = (lane < 8) ? wTB[lane] : 0;
    int iD = vD, iB = vB;
    #pragma unroll
    for (int o = 1; o < 8; o <<= 1){
      int x = __shfl_up(iD, o, 64); if (lane >= o) iD += x;
      x = __shfl_up(iB, o, 64); if (lane >= o) iB += x;
    }
    if (lane < 8){ wOD[lane] = iD - vD; wOB[lane] = iB - vB; }
  }
  __syncthreads();                                    // B7
  // ---- locate rank bins ----
  {
    int PD = wOD[wid] + incD;
    int PB = wOB[wid] + incB;
    if (doD){
      if (2799 >= PD - hD && 2799 < PD){ scI[0] = tid; scI[2] = PD - hD; }
      if (2800 >= PD - hD && 2800 < PD){ scI[1] = tid; scI[3] = PD; }
    }
    if (doB){
      if (5999 >= PB - hB && 5999 < PB){ scI[8]  = tid; scI[10] = PB - hB; }
      if (6000 >= PB - hB && 6000 < PB){ scI[9]  = tid; scI[11] = PB; }
    }
  }
  __syncthreads();                                    // B8
  const int binrD = scI[0], binr1D = scI[1], PmD = scI[2], cwinD = scI[3] - scI[2];
  const int binrB = scI[8], binr1B = scI[9], PmB = scI[10], cwinB = scI[11] - scI[10];
  const bool fastD = doD && (cwinD <= CAP);
  const bool fastB = doB && (cwinB <= CAP);
  // ---- joint collect ----
  #pragma unroll
  for (int s = 0; s < NS; ++s){
    int t = tid + (s << 9);
    if (t < TT){
      if (fastD){
        int bi = (int)(dv[s] * sclD); if (bi > NHB-1) bi = NHB-1;
        if (bi >= binrD && bi <= binr1D){ int ix = atomicAdd(&scI[4], 1); if (ix < CAP) cand[ix] = dv[s]; }
      }
      if (fastB){
        int bi = (int)(bv[s] * sclB); if (bi > NHB-1) bi = NHB-1;
        if (bi >= binrB && bi <= binr1B){ int ix = atomicAdd(&scI[12], 1); if (ix < CAP) cand[CAP + ix] = bv[s]; }
      }
    }
  }
  __syncthreads();                                    // B9
  // ---- joint exact rank ----
  if (fastD){
    int n = scI[4]; if (n > CAP) n = CAP;
    int tgt = 2799 - PmD;
    if (tid < n){
      double mv = cand[tid];
      int rk = 0;
      for (int j = 0; j < n; ++j){ double cj = cand[j]; rk += (cj < mv || (cj == mv && j < tid)) ? 1 : 0; }
      if (rk == tgt)     scD[4] = mv;
      if (rk == tgt + 1) scD[5] = mv;
    }
  }
  if (fastB){
    int n = scI[12]; if (n > CAP) n = CAP;
    int tgt = 5999 - PmB;
    if (tid < n){
      double mv = cand[CAP + tid];
      int rk = 0;
      for (int j = 0; j < n; ++j){ double cj = cand[CAP + j]; rk += (cj < mv || (cj == mv && j < tid)) ? 1 : 0; }
      if (rk == tgt)     scD[6] = mv;
      if (rk == tgt + 1) scD[7] = mv;
    }
  }
  __syncthreads();                                    // B10
  // ---- rare fallbacks ----
  if (doD && !fastD){ FALLBACK(dv, 2799, 4, maxd, 0) }
  if (doB && !fastB){ FALLBACK(bv, 5999, 6, maxb, CAP) }
  if (tid == 0){
    double gD = 0.35 * 7999.0 - 2799.0;
    double dd = scD[5] - scD[4];
    scD[2] = doD ? ((gD >= 0.5) ? (scD[5] - dd * (1.0 - gD)) : (scD[4] + dd * gD)) : 0.0;
    double gB = 0.75 * 7999.0 - 5999.0;
    double db = scD[7] - scD[6];
    scD[3] = doB ? ((gB >= 0.5) ? (scD[7] - db * (1.0 - gB)) : (scD[6] + db * gB)) : 0.0;
  }
  __syncthreads();                                    // B11
  const double dthr = scD[2], bthr = scD[3];
  // ---- flags ----
  #pragma unroll
  for (int s = 0; s < NS; ++s){
    int t = tid + (s << 9);
    if (t < TT){
      double z = (ev[s] - mu) / sd;
      bool pause  = (z <= -0.5) && (dv[s] <= dthr);
      bool voiced = (z > -0.1);
      bool bev    = (bv[s] >= bthr);
      flags[t] = (unsigned char)((pause ? 1 : 0) | (voiced ? 2 : 0) | (bev ? 4 : 0));
    }
  }
  __syncthreads();                                    // B12
  // ---- counts ----
  {
    int cp = 0, crp = 0, crs = 0, cv = 0, cb = 0;
    #pragma unroll
    for (int s = 0; s < NS; ++s){
      int t = tid + (s << 9);
      if (t < TT){
        unsigned f = flags[t];
        bool pause = (f & 1) != 0;
        bool prevP = (t > 0) ? ((flags[t-1] & 1) != 0) : false;
        cp += pause ? 1 : 0; cv += (f >> 1) & 1; cb += (f >> 2) & 1;
        if (pause && (t == 0 || !prevP)) crp++;
        if (!pause && (t == 0 || prevP)) crs++;
      }
    }
    #pragma unroll
    for (int o = 32; o; o >>= 1){
      cp += __shfl_down(cp, o, 64); crp += __shfl_down(crp, o, 64);
      crs += __shfl_down(crs, o, 64); cv += __shfl_down(cv, o, 64);
      cb += __shfl_down(cb, o, 64);
    }
    if (lane == 0){
      atomicAdd(&cnt5[0], cp); atomicAdd(&cnt5[1], crp); atomicAdd(&cnt5[2], crs);
      atomicAdd(&cnt5[3], cv); atomicAdd(&cnt5[4], cb);
    }
  }
  // ---- speech inclusive scan (contiguous 16/thread) ----
  const int t0 = tid * 16;
  int ls = 0;
  #pragma unroll
  for (int k = 0; k < 16; ++k){ int t = t0 + k; if (t < TT) ls += (flags[t] & 1) ? 0 : 1; }
  int inc = ls;
  #pragma unroll
  for (int o = 1; o < 64; o <<= 1){ int x = __shfl_up(inc, o, 64); if (lane >= o) inc += x; }
  if (lane == 63) wT[wid] = inc;
  __syncthreads();                                    // B13
  if (tid < 64){
    int v = (lane < 8) ? wT[lane] : 0;
    int i2 = v;
    #pragma unroll
    for (int o = 1; o < 8; o <<= 1){ int x = __shfl_up(i2, o, 64); if (lane >= o) i2 += x; }
    if (lane < 8) wO[lane] = i2 - v;
    if (lane == 7) scD[8] = (i2 > 1) ? (double)i2 : 1.0;
  }
  __syncthreads();                                    // B14
  const double tf = scD[8];
  {
    int run = wO[wid] + (inc - ls);
    #pragma unroll
    for (int k = 0; k < 16; ++k){
      int t = t0 + k;
      if (t < TT){ run += (flags[t] & 1) ? 0 : 1; runs[t] = (unsigned short)run; }
    }
  }
  __syncthreads();                                    // B15
  // ---- stats ----
  if (tid == 0){
    float onesP = (float)cnt5[0];
    float onesS = (float)(TT - cnt5[0]);
    float* st = out + b * 6;
    st[0] = onesP / 8000.0f;
    st[1] = (cnt5[1] > 0) ? (onesP / fmaxf((float)cnt5[1], 1.0f)) : 0.0f;
    st[2] = (cnt5[2] > 0) ? (onesS / fmaxf((float)cnt5[2], 1.0f)) : 0.0f;
    st[3] = (float)((delta_s[7997] + delta_s[7998] + delta_s[7999]) / 5.0
                  - (delta_s[0] + delta_s[1] + delta_s[2]) / 5.0);
    st[4] = ((float)cnt5[4]) / 8000.0f;
    st[5] = ((float)cnt5[3]) / 8000.0f;
  }
  // ---- trace: searchsorted + lerp ----
  if (tid < NBINS){
    double target = (tid == NBINS - 1) ? 1.0 : (double)tid * (1.0 / 23.0);
    int lo2 = 0, hi2 = TT;
    while (lo2 < hi2){
      int mid = (lo2 + hi2) >> 1;
      if ((double)runs[mid] / tf < target) lo2 = mid + 1; else hi2 = mid;
    }
    int right = lo2;
    int li = right - 1; if (li < 0) li = 0; if (li > TT-1) li = TT-1;
    int ri = right;     if (ri < 0) ri = 0; if (ri > TT-1) ri = TT-1;
    double pl = (double)runs[li] / tf, pr = (double)runs[ri] / tf;
    double denom = fabs(pr - pl); if (denom < 1e-6) denom = 1e-6;
    double alpha = (target - pl) / denom;
    if (alpha < 0.0) alpha = 0.0;
    if (alpha > 1.0) alpha = 1.0;
    if (right <= 0) alpha = 0.0;
    else if (right >= TT) alpha = 1.0;
    double fL[5], fR[5];
    for (int sdx = 0; sdx < 2; ++sdx){
      int i = sdx ? ri : li;
      double* f = sdx ? fR : fL;
      unsigned fl = flags[i];
      int j0 = i - 2; if (j0 < 0) j0 = 0;
      int j1 = i + 2; if (j1 > TT-1) j1 = TT-1;
      double ws = 0.0;
      for (int j = j0; j <= j1; ++j) ws += delta_s[j];
      f[0] = (fl & 1) ? 1.0 : 0.0;
      f[1] = ws / 5.0;
      f[2] = (fl & 4) ? 1.0 : 0.0;
      double u = (i == TT - 1) ? 1.0 : (double)i * (1.0 / 7999.0);
      f[3] = (double)runs[i] / tf - u;
      f[4] = (fl & 2) ? 1.0 : 0.0;
    }
    double om = 1.0 - alpha;
    float* tr = out + BB * 6 + ((size_t)b * NBINS + tid) * 5;
    #pragma unroll
    for (int f = 0; f < 5; ++f)
      tr[f] = (float)(fL[f] * om + fR[f] * alpha);
  }
}

extern "C" void kernel_launch(void* const* d_in, const int* in_sizes, int n_in,
                              void* d_out, int out_size, void* d_ws, size_t ws_size,
                              hipStream_t stream){
  const float* mel = (const float*)d_in[0];
  float* out = (float*)d_out;
  double* e_bt = (double*)d_ws;      // 512000 doubles = 4 MB

  hipLaunchKernelGGL(k_energy, dim3(8000), dim3(256), 0, stream, mel, e_bt);
  hipLaunchKernelGGL(k_row,    dim3(BB),   dim3(NT),  0, stream, e_bt, out);
}

// Round 7
// 51.701 us; speedup vs baseline: 1.1078x; 1.1078x over previous
//
#include <hip/hip_runtime.h>
#include <hip/hip_bf16.h>

#define TT 8000
#define BB 64
#define NBINS 24
#define CAP 256
#define NT 1024
#define NS 8     // stripes: t = tid + s*1024
#define NHB 1024 // histogram bins (one per thread)

// =================== K1: energy = mean(mel, axis=-1), LDS-staged coalesced ====================
__global__ __launch_bounds__(256) void k_energy(const float* __restrict__ mel,
                                                double* __restrict__ e_bt){
  __shared__ float sm[5120];
  const int blk = blockIdx.x, tid = threadIdx.x;
  const float4* g = (const float4*)(mel + (size_t)blk * 5120);
  float4* s4 = (float4*)sm;
  #pragma unroll
  for (int j = 0; j < 5; ++j) s4[tid + j * 256] = g[tid + j * 256];
  __syncthreads();
  const float* p = sm + tid * 20;
  double s = 0.0;
  #pragma unroll
  for (int j = 0; j < 20; ++j) s += (double)p[j];
  s += __shfl_xor(s, 1, 64);
  s += __shfl_xor(s, 2, 64);
  if ((tid & 3) == 0) e_bt[(size_t)blk * 64 + (tid >> 2)] = s / 80.0;
}

// ---- rare-path exact bisection select (round-4/5 proven), writes scD[OUTLO], scD[OUTLO+1] ----
#define FALLBACK(VALS, RNK, OUTLO, MAXV, CBASE)                                  \
  {                                                                              \
    double lo_ = -0.5, hi_ = (MAXV);                                             \
    int cl_ = 0, ch_ = 8000;                                                     \
    for (;;){                                                                    \
      if (ch_ - cl_ <= CAP){                                                     \
        if (tid == 0) redI[0] = 0;                                               \
        __syncthreads();                                                         \
        _Pragma("unroll")                                                        \
        for (int s = 0; s < NS; ++s){                                            \
          int t = tid + (s << 10);                                               \
          if (t < TT){ double v = VALS[s];                                       \
            if (v > lo_ && v <= hi_){ int ix = atomicAdd(&redI[0], 1);           \
              if (ix < CAP) cand[(CBASE) + ix] = v; } }                          \
        }                                                                        \
        __syncthreads();                                                         \
        int n = redI[0]; if (n > CAP) n = CAP;                                   \
        int tgt = (RNK) - cl_;                                                   \
        if (tid < n){                                                            \
          double mv = cand[(CBASE) + tid];                                       \
          int rk = 0;                                                            \
          for (int j = 0; j < n; ++j){ double cj = cand[(CBASE) + j];            \
            rk += (cj < mv || (cj == mv && j < tid)) ? 1 : 0; }                  \
          if (rk == tgt)     scD[OUTLO] = mv;                                    \
          if (rk == tgt + 1) scD[(OUTLO) + 1] = mv;                              \
        }                                                                        \
        __syncthreads();                                                         \
        break;                                                                   \
      }                                                                          \
      double mid_ = 0.5 * (lo_ + hi_);                                           \
      if (!(mid_ > lo_ && mid_ < hi_)){                                          \
        if (tid == 0){ scD[OUTLO] = hi_; scD[(OUTLO) + 1] = hi_; }               \
        __syncthreads();                                                         \
        break;                                                                   \
      }                                                                          \
      int c_ = 0;                                                                \
      _Pragma("unroll")                                                          \
      for (int s = 0; s < NS; ++s){                                              \
        int t = tid + (s << 10);                                                 \
        if (t < TT && VALS[s] <= mid_) c_++;                                     \
      }                                                                          \
      _Pragma("unroll")                                                          \
      for (int o = 32; o; o >>= 1) c_ += __shfl_down(c_, o, 64);                 \
      if (lane == 0) redI[wid] = c_;                                             \
      __syncthreads();                                                           \
      if (tid == 0){ int a2 = 0; for (int i = 0; i < 16; ++i) a2 += redI[i]; scI[5] = a2; } \
      __syncthreads();                                                           \
      int ct_ = scI[5];                                                          \
      if (ct_ <= (RNK)){ lo_ = mid_; cl_ = ct_; }                                \
      else if (ct_ >= (RNK) + 2){ hi_ = mid_; ch_ = ct_; }                       \
      else {                                                                     \
        double mx_ = -1.0, mn_ = 1e300;                                          \
        _Pragma("unroll")                                                        \
        for (int s = 0; s < NS; ++s){                                            \
          int t = tid + (s << 10);                                               \
          if (t < TT){ double v = VALS[s];                                       \
            if (v <= mid_){ if (v > mx_) mx_ = v; } else { if (v < mn_) mn_ = v; } } \
        }                                                                        \
        _Pragma("unroll")                                                        \
        for (int o = 32; o; o >>= 1){ double x = __shfl_down(mx_, o, 64); if (x > mx_) mx_ = x; } \
        if (lane == 0) redD[wid] = mx_;                                          \
        __syncthreads();                                                         \
        if (tid == 0){ double a2 = redD[0]; for (int i = 1; i < 16; ++i) if (redD[i] > a2) a2 = redD[i]; scD[OUTLO] = a2; } \
        __syncthreads();                                                         \
        _Pragma("unroll")                                                        \
        for (int o = 32; o; o >>= 1){ double x = __shfl_down(mn_, o, 64); if (x < mn_) mn_ = x; } \
        if (lane == 0) redD[wid] = mn_;                                          \
        __syncthreads();                                                         \
        if (tid == 0){ double a2 = redD[0]; for (int i = 1; i < 16; ++i) if (redD[i] < a2) a2 = redD[i]; scD[(OUTLO) + 1] = a2; } \
        __syncthreads();                                                         \
        break;                                                                   \
      }                                                                          \
    }                                                                            \
  }

// =================== K2: one block per row, 16 waves, joint quantile pass ====================
__global__ __launch_bounds__(NT) void k_row(const double* __restrict__ e_all,
                                            float* __restrict__ out){
  __shared__ double e_s[TT];                          // 64000 B
  __shared__ double delta_s[TT];                      // 64000 B
  __shared__ __align__(16) unsigned short runs[TT];   // 16000 B (aliased as hists early)
  __shared__ unsigned char flags[TT];                 //  8000 B
  __shared__ double cand[2 * CAP];                    //  4096 B  [0:CAP) D, [CAP:2CAP) B
  __shared__ double redD[64];
  __shared__ int    redI[16];
  __shared__ double scD[12];  // 0 mu 1 sd 2 dthr 3 bthr 4 dlo 5 dhi 6 blo 7 bhi 8 tf 9 maxd 10 maxb
  __shared__ int    scI[16];  // 0-3 D locate | 4 candND | 5 fb-count | 8-11 B locate | 12 candNB
  __shared__ int    wTD[16], wOD[16], wTB[16], wOB[16], wT[16], wO[16];
  __shared__ int    cnt5[5];
  int* histD = (int*)runs;        // 4096 B
  int* histB = histD + NHB;       // 4096 B  (runs unused until after quantiles)

  const int b = blockIdx.x, tid = threadIdx.x;
  const int lane = tid & 63, wid = tid >> 6;
  const double* eg = e_all + (size_t)b * TT;

  if (tid < 5) cnt5[tid] = 0;
  if (tid < 16) scI[tid] = 0;
  histD[tid] = 0; histB[tid] = 0;                     // tid<1024 covers both fully

  double ev[NS], dv[NS], bv[NS];
  // ---- load e (striped: lane-consecutive) ----
  #pragma unroll
  for (int s = 0; s < NS; ++s){
    int t = tid + (s << 10);
    double e = (t < TT) ? eg[t] : 0.0;
    ev[s] = e;
    if (t < TT) e_s[t] = e;
  }
  __syncthreads();                                    // B1
  // ---- delta ----
  #pragma unroll
  for (int s = 0; s < NS; ++s){
    int t = tid + (s << 10);
    double d = 0.0;
    if (t > 0 && t < TT) d = fabs(e_s[t] - e_s[t-1]);
    dv[s] = d;
    if (t < TT) delta_s[t] = d;
  }
  __syncthreads();                                    // B2
  // ---- bs (window-7 mean) ----
  #pragma unroll
  for (int s = 0; s < NS; ++s){
    int t = tid + (s << 10);
    double sum = 0.0;
    if (t < TT){
      int j0 = t - 3; if (j0 < 0) j0 = 0;
      int j1 = t + 3; if (j1 > TT-1) j1 = TT-1;
      for (int j = j0; j <= j1; ++j) sum += delta_s[j];
    }
    bv[s] = sum / 7.0;
  }
  // ---- fused reduce: sum(e), sum(e^2), max(dv), max(bv) ----
  {
    double se = 0.0, s2 = 0.0, md = 0.0, mb = 0.0;
    #pragma unroll
    for (int s = 0; s < NS; ++s){
      se += ev[s]; s2 += ev[s] * ev[s];
      if (dv[s] > md) md = dv[s];
      if (bv[s] > mb) mb = bv[s];
    }
    #pragma unroll
    for (int o = 32; o; o >>= 1){
      se += __shfl_down(se, o, 64);
      s2 += __shfl_down(s2, o, 64);
      double x = __shfl_down(md, o, 64); if (x > md) md = x;
      x = __shfl_down(mb, o, 64); if (x > mb) mb = x;
    }
    if (lane == 0){ redD[wid] = se; redD[16+wid] = s2; redD[32+wid] = md; redD[48+wid] = mb; }
  }
  __syncthreads();                                    // B3
  if (tid < 64){
    double a = (lane < 16) ? redD[lane]      : 0.0;
    double q = (lane < 16) ? redD[16 + lane] : 0.0;
    double c = (lane < 16) ? redD[32 + lane] : 0.0;
    double d = (lane < 16) ? redD[48 + lane] : 0.0;
    #pragma unroll
    for (int o = 8; o; o >>= 1){
      a += __shfl_down(a, o, 64);
      q += __shfl_down(q, o, 64);
      double x = __shfl_down(c, o, 64); if (x > c) c = x;
      x = __shfl_down(d, o, 64); if (x > d) d = x;
    }
    if (lane == 0){
      double mu0 = a / 8000.0;
      double var = (q - a * a / 8000.0) / 7999.0;
      if (var < 0.0) var = 0.0;
      double sd0 = sqrt(var); if (sd0 < 1e-6) sd0 = 1e-6;
      scD[0] = mu0; scD[1] = sd0; scD[9] = c; scD[10] = d;
    }
  }
  __syncthreads();                                    // B4
  const double mu = scD[0], sd = scD[1];
  const double maxd = scD[9], maxb = scD[10];
  const bool doD = (maxd > 0.0), doB = (maxb > 0.0);
  const double sclD = doD ? (double)NHB / maxd : 0.0;
  const double sclB = doB ? (double)NHB / maxb : 0.0;
  // ---- joint histogram fill (one sweep) ----
  #pragma unroll
  for (int s = 0; s < NS; ++s){
    int t = tid + (s << 10);
    if (t < TT){
      if (doD){ int bi = (int)(dv[s] * sclD); if (bi > NHB-1) bi = NHB-1; atomicAdd(&histD[bi], 1); }
      if (doB){ int bi = (int)(bv[s] * sclB); if (bi > NHB-1) bi = NHB-1; atomicAdd(&histB[bi], 1); }
    }
  }
  __syncthreads();                                    // B5
  // ---- joint scan of both 1024-bin hists (one bin per thread) ----
  const int hD = histD[tid], hB = histB[tid];
  int incD = hD, incB = hB;
  #pragma unroll
  for (int o = 1; o < 64; o <<= 1){
    int x = __shfl_up(incD, o, 64); if (lane >= o) incD += x;
    x = __shfl_up(incB, o, 64); if (lane >= o) incB += x;
  }
  if (lane == 63){ wTD[wid] = incD; wTB[wid] = incB; }
  __syncthreads();                                    // B6
  if (tid < 64){
    int vD = (lane < 16) ? wTD[lane] : 0;
    int vB = (lane < 16) ? wTB[lane] : 0;
    int iD = vD, iB = vB;
    #pragma unroll
    for (int o = 1; o < 16; o <<= 1){
      int x = __shfl_up(iD, o, 64); if (lane >= o) iD += x;
      x = __shfl_up(iB, o, 64); if (lane >= o) iB += x;
    }
    if (lane < 16){ wOD[lane] = iD - vD; wOB[lane] = iB - vB; }
  }
  __syncthreads();                                    // B7
  // ---- locate rank bins ----
  {
    int PD = wOD[wid] + incD;
    int PB = wOB[wid] + incB;
    if (doD){
      if (2799 >= PD - hD && 2799 < PD){ scI[0] = tid; scI[2] = PD - hD; }
      if (2800 >= PD - hD && 2800 < PD){ scI[1] = tid; scI[3] = PD; }
    }
    if (doB){
      if (5999 >= PB - hB && 5999 < PB){ scI[8]  = tid; scI[10] = PB - hB; }
      if (6000 >= PB - hB && 6000 < PB){ scI[9]  = tid; scI[11] = PB; }
    }
  }
  __syncthreads();                                    // B8
  const int binrD = scI[0], binr1D = scI[1], PmD = scI[2], cwinD = scI[3] - scI[2];
  const int binrB = scI[8], binr1B = scI[9], PmB = scI[10], cwinB = scI[11] - scI[10];
  const bool fastD = doD && (cwinD <= CAP);
  const bool fastB = doB && (cwinB <= CAP);
  // ---- joint collect ----
  #pragma unroll
  for (int s = 0; s < NS; ++s){
    int t = tid + (s << 10);
    if (t < TT){
      if (fastD){
        int bi = (int)(dv[s] * sclD); if (bi > NHB-1) bi = NHB-1;
        if (bi >= binrD && bi <= binr1D){ int ix = atomicAdd(&scI[4], 1); if (ix < CAP) cand[ix] = dv[s]; }
      }
      if (fastB){
        int bi = (int)(bv[s] * sclB); if (bi > NHB-1) bi = NHB-1;
        if (bi >= binrB && bi <= binr1B){ int ix = atomicAdd(&scI[12], 1); if (ix < CAP) cand[CAP + ix] = bv[s]; }
      }
    }
  }
  __syncthreads();                                    // B9
  // ---- joint exact rank ----
  if (fastD){
    int n = scI[4]; if (n > CAP) n = CAP;
    int tgt = 2799 - PmD;
    if (tid < n){
      double mv = cand[tid];
      int rk = 0;
      for (int j = 0; j < n; ++j){ double cj = cand[j]; rk += (cj < mv || (cj == mv && j < tid)) ? 1 : 0; }
      if (rk == tgt)     scD[4] = mv;
      if (rk == tgt + 1) scD[5] = mv;
    }
  }
  if (fastB){
    int n = scI[12]; if (n > CAP) n = CAP;
    int tgt = 5999 - PmB;
    if (tid < n){
      double mv = cand[CAP + tid];
      int rk = 0;
      for (int j = 0; j < n; ++j){ double cj = cand[CAP + j]; rk += (cj < mv || (cj == mv && j < tid)) ? 1 : 0; }
      if (rk == tgt)     scD[6] = mv;
      if (rk == tgt + 1) scD[7] = mv;
    }
  }
  __syncthreads();                                    // B10
  // ---- rare fallbacks ----
  if (doD && !fastD){ FALLBACK(dv, 2799, 4, maxd, 0) }
  if (doB && !fastB){ FALLBACK(bv, 5999, 6, maxb, CAP) }
  if (tid == 0){
    double gD = 0.35 * 7999.0 - 2799.0;
    double dd = scD[5] - scD[4];
    scD[2] = doD ? ((gD >= 0.5) ? (scD[5] - dd * (1.0 - gD)) : (scD[4] + dd * gD)) : 0.0;
    double gB = 0.75 * 7999.0 - 5999.0;
    double db = scD[7] - scD[6];
    scD[3] = doB ? ((gB >= 0.5) ? (scD[7] - db * (1.0 - gB)) : (scD[6] + db * gB)) : 0.0;
  }
  __syncthreads();                                    // B11
  const double dthr = scD[2], bthr = scD[3];
  // ---- flags ----
  #pragma unroll
  for (int s = 0; s < NS; ++s){
    int t = tid + (s << 10);
    if (t < TT){
      double z = (ev[s] - mu) / sd;
      bool pause  = (z <= -0.5) && (dv[s] <= dthr);
      bool voiced = (z > -0.1);
      bool bev    = (bv[s] >= bthr);
      flags[t] = (unsigned char)((pause ? 1 : 0) | (voiced ? 2 : 0) | (bev ? 4 : 0));
    }
  }
  __syncthreads();                                    // B12
  // ---- counts ----
  {
    int cp = 0, crp = 0, crs = 0, cv = 0, cb = 0;
    #pragma unroll
    for (int s = 0; s < NS; ++s){
      int t = tid + (s << 10);
      if (t < TT){
        unsigned f = flags[t];
        bool pause = (f & 1) != 0;
        bool prevP = (t > 0) ? ((flags[t-1] & 1) != 0) : false;
        cp += pause ? 1 : 0; cv += (f >> 1) & 1; cb += (f >> 2) & 1;
        if (pause && (t == 0 || !prevP)) crp++;
        if (!pause && (t == 0 || prevP)) crs++;
      }
    }
    #pragma unroll
    for (int o = 32; o; o >>= 1){
      cp += __shfl_down(cp, o, 64); crp += __shfl_down(crp, o, 64);
      crs += __shfl_down(crs, o, 64); cv += __shfl_down(cv, o, 64);
      cb += __shfl_down(cb, o, 64);
    }
    if (lane == 0){
      atomicAdd(&cnt5[0], cp); atomicAdd(&cnt5[1], crp); atomicAdd(&cnt5[2], crs);
      atomicAdd(&cnt5[3], cv); atomicAdd(&cnt5[4], cb);
    }
  }
  // ---- speech inclusive scan (contiguous 8/thread) ----
  const int t0 = tid * 8;
  int ls = 0;
  if (t0 < TT){
    #pragma unroll
    for (int k = 0; k < 8; ++k) ls += (flags[t0 + k] & 1) ? 0 : 1;
  }
  int inc = ls;
  #pragma unroll
  for (int o = 1; o < 64; o <<= 1){ int x = __shfl_up(inc, o, 64); if (lane >= o) inc += x; }
  if (lane == 63) wT[wid] = inc;
  __syncthreads();                                    // B13
  if (tid < 64){
    int v = (lane < 16) ? wT[lane] : 0;
    int i2 = v;
    #pragma unroll
    for (int o = 1; o < 16; o <<= 1){ int x = __shfl_up(i2, o, 64); if (lane >= o) i2 += x; }
    if (lane < 16) wO[lane] = i2 - v;
    if (lane == 15) scD[8] = (i2 > 1) ? (double)i2 : 1.0;
  }
  __syncthreads();                                    // B14
  const double tf = scD[8];
  if (t0 < TT){
    int run = wO[wid] + (inc - ls);
    #pragma unroll
    for (int k = 0; k < 8; ++k){
      int t = t0 + k;
      run += (flags[t] & 1) ? 0 : 1;
      runs[t] = (unsigned short)run;
    }
  }
  __syncthreads();                                    // B15
  // ---- stats ----
  if (tid == 0){
    float onesP = (float)cnt5[0];
    float onesS = (float)(TT - cnt5[0]);
    float* st = out + b * 6;
    st[0] = onesP / 8000.0f;
    st[1] = (cnt5[1] > 0) ? (onesP / fmaxf((float)cnt5[1], 1.0f)) : 0.0f;
    st[2] = (cnt5[2] > 0) ? (onesS / fmaxf((float)cnt5[2], 1.0f)) : 0.0f;
    st[3] = (float)((delta_s[7997] + delta_s[7998] + delta_s[7999]) / 5.0
                  - (delta_s[0] + delta_s[1] + delta_s[2]) / 5.0);
    st[4] = ((float)cnt5[4]) / 8000.0f;
    st[5] = ((float)cnt5[3]) / 8000.0f;
  }
  // ---- trace: searchsorted + lerp ----
  if (tid < NBINS){
    double target = (tid == NBINS - 1) ? 1.0 : (double)tid * (1.0 / 23.0);
    int lo2 = 0, hi2 = TT;
    while (lo2 < hi2){
      int mid = (lo2 + hi2) >> 1;
      if ((double)runs[mid] / tf < target) lo2 = mid + 1; else hi2 = mid;
    }
    int right = lo2;
    int li = right - 1; if (li < 0) li = 0; if (li > TT-1) li = TT-1;
    int ri = right;     if (ri < 0) ri = 0; if (ri > TT-1) ri = TT-1;
    double pl = (double)runs[li] / tf, pr = (double)runs[ri] / tf;
    double denom = fabs(pr - pl); if (denom < 1e-6) denom = 1e-6;
    double alpha = (target - pl) / denom;
    if (alpha < 0.0) alpha = 0.0;
    if (alpha > 1.0) alpha = 1.0;
    if (right <= 0) alpha = 0.0;
    else if (right >= TT) alpha = 1.0;
    double fL[5], fR[5];
    for (int sdx = 0; sdx < 2; ++sdx){
      int i = sdx ? ri : li;
      double* f = sdx ? fR : fL;
      unsigned fl = flags[i];
      int j0 = i - 2; if (j0 < 0) j0 = 0;
      int j1 = i + 2; if (j1 > TT-1) j1 = TT-1;
      double ws = 0.0;
      for (int j = j0; j <= j1; ++j) ws += delta_s[j];
      f[0] = (fl & 1) ? 1.0 : 0.0;
      f[1] = ws / 5.0;
      f[2] = (fl & 4) ? 1.0 : 0.0;
      double u = (i == TT - 1) ? 1.0 : (double)i * (1.0 / 7999.0);
      f[3] = (double)runs[i] / tf - u;
      f[4] = (fl & 2) ? 1.0 : 0.0;
    }
    double om = 1.0 - alpha;
    float* tr = out + BB * 6 + ((size_t)b * NBINS + tid) * 5;
    #pragma unroll
    for (int f = 0; f < 5; ++f)
      tr[f] = (float)(fL[f] * om + fR[f] * alpha);
  }
}

extern "C" void kernel_launch(void* const* d_in, const int* in_sizes, int n_in,
                              void* d_out, int out_size, void* d_ws, size_t ws_size,
                              hipStream_t stream){
  const float* mel = (const float*)d_in[0];
  float* out = (float*)d_out;
  double* e_bt = (double*)d_ws;      // 512000 doubles = 4 MB

  hipLaunchKernelGGL(k_energy, dim3(8000), dim3(256), 0, stream, mel, e_bt);
  hipLaunchKernelGGL(k_row,    dim3(BB),   dim3(NT),  0, stream, e_bt, out);
}

// Round 8
// 51.046 us; speedup vs baseline: 1.1221x; 1.0128x over previous
//
#include <hip/hip_runtime.h>
#include <hip/hip_bf16.h>

#define TT 8000
#define BB 64
#define NBINS 24
#define CAP 256
#define NT 1024
#define NS 8      // stripes: t = tid + s*1024
#define NHB 1024  // histogram bins (one per thread)
#define FSCALE 1024.0  // fixed bin scale (power of 2 -> exact)

// =================== K1: energy = mean(mel, axis=-1), LDS-staged coalesced ====================
__global__ __launch_bounds__(256) void k_energy(const float* __restrict__ mel,
                                                double* __restrict__ e_bt){
  __shared__ float sm[5120];
  const int blk = blockIdx.x, tid = threadIdx.x;
  const float4* g = (const float4*)(mel + (size_t)blk * 5120);
  float4* s4 = (float4*)sm;
  #pragma unroll
  for (int j = 0; j < 5; ++j) s4[tid + j * 256] = g[tid + j * 256];
  __syncthreads();
  const float* p = sm + tid * 20;
  double s = 0.0;
  #pragma unroll
  for (int j = 0; j < 20; ++j) s += (double)p[j];
  s += __shfl_xor(s, 1, 64);
  s += __shfl_xor(s, 2, 64);
  if ((tid & 3) == 0) e_bt[(size_t)blk * 64 + (tid >> 2)] = s / 80.0;
}

// ---- rare-path exact bisection select (round-4..7 proven); computes its own max ----
#define FALLBACK(VALS, RNK, OUTLO, CBASE)                                        \
  {                                                                              \
    double mx0 = 0.0;                                                            \
    _Pragma("unroll")                                                            \
    for (int s = 0; s < NS; ++s){                                                \
      int t = tid + (s << 10);                                                   \
      if (t < TT && VALS[s] > mx0) mx0 = VALS[s];                                \
    }                                                                            \
    _Pragma("unroll")                                                            \
    for (int o = 32; o; o >>= 1){ double x = __shfl_down(mx0, o, 64); if (x > mx0) mx0 = x; } \
    if (lane == 0) redD[wid] = mx0;                                              \
    __syncthreads();                                                             \
    if (tid == 0){ double a2 = redD[0]; for (int i = 1; i < 16; ++i) if (redD[i] > a2) a2 = redD[i]; scD[11] = a2; } \
    __syncthreads();                                                             \
    double lo_ = -0.5, hi_ = scD[11];                                            \
    int cl_ = 0, ch_ = 8000;                                                     \
    for (;;){                                                                    \
      if (ch_ - cl_ <= CAP){                                                     \
        if (tid == 0) redI[0] = 0;                                               \
        __syncthreads();                                                         \
        _Pragma("unroll")                                                        \
        for (int s = 0; s < NS; ++s){                                            \
          int t = tid + (s << 10);                                               \
          if (t < TT){ double v = VALS[s];                                       \
            if (v > lo_ && v <= hi_){ int ix = atomicAdd(&redI[0], 1);           \
              if (ix < CAP) cand[(CBASE) + ix] = v; } }                          \
        }                                                                        \
        __syncthreads();                                                         \
        int n = redI[0]; if (n > CAP) n = CAP;                                   \
        int tgt = (RNK) - cl_;                                                   \
        if (tid < n){                                                            \
          double mv = cand[(CBASE) + tid];                                       \
          int rk = 0;                                                            \
          for (int j = 0; j < n; ++j){ double cj = cand[(CBASE) + j];            \
            rk += (cj < mv || (cj == mv && j < tid)) ? 1 : 0; }                  \
          if (rk == tgt)     scD[OUTLO] = mv;                                    \
          if (rk == tgt + 1) scD[(OUTLO) + 1] = mv;                              \
        }                                                                        \
        __syncthreads();                                                         \
        break;                                                                   \
      }                                                                          \
      double mid_ = 0.5 * (lo_ + hi_);                                           \
      if (!(mid_ > lo_ && mid_ < hi_)){                                          \
        if (tid == 0){ scD[OUTLO] = hi_; scD[(OUTLO) + 1] = hi_; }               \
        __syncthreads();                                                         \
        break;                                                                   \
      }                                                                          \
      int c_ = 0;                                                                \
      _Pragma("unroll")                                                          \
      for (int s = 0; s < NS; ++s){                                              \
        int t = tid + (s << 10);                                                 \
        if (t < TT && VALS[s] <= mid_) c_++;                                     \
      }                                                                          \
      _Pragma("unroll")                                                          \
      for (int o = 32; o; o >>= 1) c_ += __shfl_down(c_, o, 64);                 \
      if (lane == 0) redI[wid] = c_;                                             \
      __syncthreads();                                                           \
      if (tid == 0){ int a2 = 0; for (int i = 0; i < 16; ++i) a2 += redI[i]; scI[5] = a2; } \
      __syncthreads();                                                           \
      int ct_ = scI[5];                                                          \
      if (ct_ <= (RNK)){ lo_ = mid_; cl_ = ct_; }                                \
      else if (ct_ >= (RNK) + 2){ hi_ = mid_; ch_ = ct_; }                       \
      else {                                                                     \
        double mx_ = -1.0, mn_ = 1e300;                                          \
        _Pragma("unroll")                                                        \
        for (int s = 0; s < NS; ++s){                                            \
          int t = tid + (s << 10);                                               \
          if (t < TT){ double v = VALS[s];                                       \
            if (v <= mid_){ if (v > mx_) mx_ = v; } else { if (v < mn_) mn_ = v; } } \
        }                                                                        \
        _Pragma("unroll")                                                        \
        for (int o = 32; o; o >>= 1){ double x = __shfl_down(mx_, o, 64); if (x > mx_) mx_ = x; } \
        if (lane == 0) redD[wid] = mx_;                                          \
        __syncthreads();                                                         \
        if (tid == 0){ double a2 = redD[0]; for (int i = 1; i < 16; ++i) if (redD[i] > a2) a2 = redD[i]; scD[OUTLO] = a2; } \
        __syncthreads();                                                         \
        _Pragma("unroll")                                                        \
        for (int o = 32; o; o >>= 1){ double x = __shfl_down(mn_, o, 64); if (x < mn_) mn_ = x; } \
        if (lane == 0) redD[wid] = mn_;                                          \
        __syncthreads();                                                         \
        if (tid == 0){ double a2 = redD[0]; for (int i = 1; i < 16; ++i) if (redD[i] < a2) a2 = redD[i]; scD[(OUTLO) + 1] = a2; } \
        __syncthreads();                                                         \
        break;                                                                   \
      }                                                                          \
    }                                                                            \
  }

// =================== K2: one block per row, 16 waves, 9-barrier pipeline ====================
__global__ __launch_bounds__(NT) void k_row(const double* __restrict__ e_all,
                                            float* __restrict__ out){
  __shared__ double e_s[TT];                          // 64000 B (boundary reads only)
  __shared__ double delta_s[TT];                      // 64000 B
  __shared__ __align__(16) unsigned short runs[TT];   // 16000 B (aliased as hists early)
  __shared__ unsigned char flags[TT];                 //  8000 B
  __shared__ double cand[2 * CAP];                    //  4096 B
  __shared__ double redD[32];
  __shared__ int    redI[16];
  __shared__ double scD[12];  // 0 mu 1 sd | 4 dlo 5 dhi 6 blo 7 bhi | 11 fb-max
  __shared__ int    scI[16];  // 0-3 D locate | 4 candND 5 fbC | 8-11 B locate | 12 candNB
  __shared__ int    wTD[16], wTB[16], wT[16];
  __shared__ int    cnt5[5];
  int* histD = (int*)runs;        // 4096 B
  int* histB = histD + NHB;       // 4096 B (runs unused until after quantiles)

  const int b = blockIdx.x, tid = threadIdx.x;
  const int lane = tid & 63, wid = tid >> 6;
  const double* eg = e_all + (size_t)b * TT;

  if (tid < 5) cnt5[tid] = 0;
  if (tid < 16) scI[tid] = 0;
  histD[tid] = 0; histB[tid] = 0;

  double ev[NS], dv[NS], bv[NS];
  // ---- load e + delta (shfl; lane-0 boundary from global) ----
  #pragma unroll
  for (int s = 0; s < NS; ++s){
    int t = tid + (s << 10);
    double e = (t < TT) ? eg[t] : 0.0;
    ev[s] = e;
    if (t < TT) e_s[t] = e;
  }
  #pragma unroll
  for (int s = 0; s < NS; ++s){
    int t = tid + (s << 10);
    double ep = __shfl_up(ev[s], 1, 64);
    if (lane == 0 && t > 0 && t < TT) ep = eg[t - 1];
    double d = (t > 0 && t < TT) ? fabs(ev[s] - ep) : 0.0;
    dv[s] = d;
    if (t < TT) delta_s[t] = d;
  }
  __syncthreads();                                    // B1
  // ---- Phase1: bs windows + joint hist fill (fixed scale) + sum/sum2 reduce ----
  {
    double se = 0.0, s2 = 0.0;
    #pragma unroll
    for (int s = 0; s < NS; ++s){
      int t = tid + (s << 10);
      double bw = 0.0;
      if (t < TT){
        int j0 = t - 3; if (j0 < 0) j0 = 0;
        int j1 = t + 3; if (j1 > TT - 1) j1 = TT - 1;
        double sum = 0.0;
        for (int j = j0; j <= j1; ++j) sum += delta_s[j];
        bw = sum / 7.0;
        int biD = (int)(dv[s] * FSCALE); if (biD > NHB - 1) biD = NHB - 1;
        atomicAdd(&histD[biD], 1);
        int biB = (int)(bw * FSCALE); if (biB > NHB - 1) biB = NHB - 1;
        atomicAdd(&histB[biB], 1);
        se += ev[s]; s2 += ev[s] * ev[s];
      }
      bv[s] = bw;
    }
    #pragma unroll
    for (int o = 32; o; o >>= 1){ se += __shfl_down(se, o, 64); s2 += __shfl_down(s2, o, 64); }
    if (lane == 0){ redD[wid] = se; redD[16 + wid] = s2; }
  }
  __syncthreads();                                    // B2
  // ---- Phase2: hist scans (bin=tid) + mu/sd fold by wave 0 ----
  const int hD = histD[tid], hB = histB[tid];
  int incD = hD, incB = hB;
  #pragma unroll
  for (int o = 1; o < 64; o <<= 1){
    int x = __shfl_up(incD, o, 64); if (lane >= o) incD += x;
    x = __shfl_up(incB, o, 64); if (lane >= o) incB += x;
  }
  if (lane == 63){ wTD[wid] = incD; wTB[wid] = incB; }
  if (tid < 64){
    double a = (lane < 16) ? redD[lane] : 0.0;
    double q = (lane < 16) ? redD[16 + lane] : 0.0;
    #pragma unroll
    for (int o = 8; o; o >>= 1){ a += __shfl_down(a, o, 64); q += __shfl_down(q, o, 64); }
    if (lane == 0){
      double mu0 = a / 8000.0;
      double var = (q - a * a / 8000.0) / 7999.0;
      if (var < 0.0) var = 0.0;
      double sd0 = sqrt(var); if (sd0 < 1e-6) sd0 = 1e-6;
      scD[0] = mu0; scD[1] = sd0;
    }
  }
  __syncthreads();                                    // B3
  // ---- Phase3: per-thread wave-offset fold + locate rank bins ----
  {
    int preD = 0, preB = 0;
    #pragma unroll
    for (int i = 0; i < 16; ++i){ if (i < wid){ preD += wTD[i]; preB += wTB[i]; } }
    int PD = preD + incD, PB = preB + incB;           // inclusive prefix for bin tid
    if (2799 >= PD - hD && 2799 < PD){ scI[0] = tid; scI[2] = PD - hD; }
    if (2800 >= PD - hD && 2800 < PD){ scI[1] = tid; scI[3] = PD; }
    if (5999 >= PB - hB && 5999 < PB){ scI[8]  = tid; scI[10] = PB - hB; }
    if (6000 >= PB - hB && 6000 < PB){ scI[9]  = tid; scI[11] = PB; }
  }
  __syncthreads();                                    // B4
  const int binrD = scI[0], binr1D = scI[1], PmD = scI[2], cwinD = scI[3] - scI[2];
  const int binrB = scI[8], binr1B = scI[9], PmB = scI[10], cwinB = scI[11] - scI[10];
  const bool fastD = (cwinD <= CAP), fastB = (cwinB <= CAP);
  // ---- Phase4: joint collect ----
  #pragma unroll
  for (int s = 0; s < NS; ++s){
    int t = tid + (s << 10);
    if (t < TT){
      if (fastD){
        int bi = (int)(dv[s] * FSCALE); if (bi > NHB - 1) bi = NHB - 1;
        if (bi >= binrD && bi <= binr1D){ int ix = atomicAdd(&scI[4], 1); if (ix < CAP) cand[ix] = dv[s]; }
      }
      if (fastB){
        int bi = (int)(bv[s] * FSCALE); if (bi > NHB - 1) bi = NHB - 1;
        if (bi >= binrB && bi <= binr1B){ int ix = atomicAdd(&scI[12], 1); if (ix < CAP) cand[CAP + ix] = bv[s]; }
      }
    }
  }
  __syncthreads();                                    // B5
  // ---- Phase5: exact rank ----
  if (fastD){
    int n = scI[4]; if (n > CAP) n = CAP;
    int tgt = 2799 - PmD;
    if (tid < n){
      double mv = cand[tid];
      int rk = 0;
      for (int j = 0; j < n; ++j){ double cj = cand[j]; rk += (cj < mv || (cj == mv && j < tid)) ? 1 : 0; }
      if (rk == tgt)     scD[4] = mv;
      if (rk == tgt + 1) scD[5] = mv;
    }
  }
  if (fastB){
    int n = scI[12]; if (n > CAP) n = CAP;
    int tgt = 5999 - PmB;
    if (tid < n){
      double mv = cand[CAP + tid];
      int rk = 0;
      for (int j = 0; j < n; ++j){ double cj = cand[CAP + j]; rk += (cj < mv || (cj == mv && j < tid)) ? 1 : 0; }
      if (rk == tgt)     scD[6] = mv;
      if (rk == tgt + 1) scD[7] = mv;
    }
  }
  __syncthreads();                                    // B6
  // ---- rare fallbacks (block-uniform) ----
  if (!fastD){ FALLBACK(dv, 2799, 4, 0) }
  if (!fastB){ FALLBACK(bv, 5999, 6, CAP) }
  // ---- thresholds: every thread computes locally (numpy _lerp) ----
  const double mu = scD[0], sd = scD[1];
  const double gD = 0.35 * 7999.0 - 2799.0;
  const double dd = scD[5] - scD[4];
  const double dthr = (gD >= 0.5) ? (scD[5] - dd * (1.0 - gD)) : (scD[4] + dd * gD);
  const double gB = 0.75 * 7999.0 - 5999.0;
  const double db = scD[7] - scD[6];
  const double bthr = (gB >= 0.5) ? (scD[7] - db * (1.0 - gB)) : (scD[6] + db * gB);
  // ---- Phase6: flags + counts (register masks; prevP via shfl, lane0 recompute) ----
  unsigned pmask = 0, vmask = 0, bmask = 0;
  #pragma unroll
  for (int s = 0; s < NS; ++s){
    int t = tid + (s << 10);
    if (t < TT){
      double z = (ev[s] - mu) / sd;
      bool pause  = (z <= -0.5) && (dv[s] <= dthr);
      bool voiced = (z > -0.1);
      bool bev    = (bv[s] >= bthr);
      if (pause)  pmask |= 1u << s;
      if (voiced) vmask |= 1u << s;
      if (bev)    bmask |= 1u << s;
      flags[t] = (unsigned char)((pause ? 1 : 0) | (voiced ? 2 : 0) | (bev ? 4 : 0));
    }
  }
  {
    unsigned pprev = __shfl_up(pmask, 1, 64);
    int cp = 0, crp = 0, crs = 0, cv = 0, cb = 0;
    #pragma unroll
    for (int s = 0; s < NS; ++s){
      int t = tid + (s << 10);
      if (t < TT){
        bool pause = (pmask >> s) & 1;
        cp += (pmask >> s) & 1; cv += (vmask >> s) & 1; cb += (bmask >> s) & 1;
        bool prevP = false;
        if (t > 0){
          if (lane == 0){
            double zp = (e_s[t - 1] - mu) / sd;
            prevP = (zp <= -0.5) && (delta_s[t - 1] <= dthr);
          } else prevP = (pprev >> s) & 1;
        }
        if (pause && (t == 0 || !prevP)) crp++;
        if (!pause && (t == 0 || prevP)) crs++;
      }
    }
    #pragma unroll
    for (int o = 32; o; o >>= 1){
      cp += __shfl_down(cp, o, 64); crp += __shfl_down(crp, o, 64);
      crs += __shfl_down(crs, o, 64); cv += __shfl_down(cv, o, 64);
      cb += __shfl_down(cb, o, 64);
    }
    if (lane == 0){
      atomicAdd(&cnt5[0], cp); atomicAdd(&cnt5[1], crp); atomicAdd(&cnt5[2], crs);
      atomicAdd(&cnt5[3], cv); atomicAdd(&cnt5[4], cb);
    }
  }
  __syncthreads();                                    // B7
  // ---- Phase7: stats (tid0) + speech scan (contiguous 8/thread) ----
  const int t0 = tid * 8;
  int ls = 0;
  if (t0 < TT){
    #pragma unroll
    for (int k = 0; k < 8; ++k) ls += (flags[t0 + k] & 1) ? 0 : 1;
  }
  int inc = ls;
  #pragma unroll
  for (int o = 1; o < 64; o <<= 1){ int x = __shfl_up(inc, o, 64); if (lane >= o) inc += x; }
  if (lane == 63) wT[wid] = inc;
  if (tid == 0){
    float onesP = (float)cnt5[0];
    float onesS = (float)(TT - cnt5[0]);
    float* st = out + b * 6;
    st[0] = onesP / 8000.0f;
    st[1] = (cnt5[1] > 0) ? (onesP / fmaxf((float)cnt5[1], 1.0f)) : 0.0f;
    st[2] = (cnt5[2] > 0) ? (onesS / fmaxf((float)cnt5[2], 1.0f)) : 0.0f;
    st[3] = (float)((delta_s[7997] + delta_s[7998] + delta_s[7999]) / 5.0
                  - (delta_s[0] + delta_s[1] + delta_s[2]) / 5.0);
    st[4] = ((float)cnt5[4]) / 8000.0f;
    st[5] = ((float)cnt5[3]) / 8000.0f;
  }
  __syncthreads();                                    // B8
  // ---- Phase8: per-thread wave-offset fold + runs write ----
  int totAll = 0, pre = 0;
  #pragma unroll
  for (int i = 0; i < 16; ++i){ int v = wT[i]; totAll += v; if (i < wid) pre += v; }
  const double tf = (totAll > 1) ? (double)totAll : 1.0;
  if (t0 < TT){
    int run = pre + (inc - ls);
    #pragma unroll
    for (int k = 0; k < 8; ++k){
      int t = t0 + k;
      run += (flags[t] & 1) ? 0 : 1;
      runs[t] = (unsigned short)run;
    }
  }
  __syncthreads();                                    // B9
  // ---- Phase9: trace (searchsorted + lerp) ----
  if (tid < NBINS){
    double target = (tid == NBINS - 1) ? 1.0 : (double)tid * (1.0 / 23.0);
    int lo2 = 0, hi2 = TT;
    while (lo2 < hi2){
      int mid = (lo2 + hi2) >> 1;
      if ((double)runs[mid] / tf < target) lo2 = mid + 1; else hi2 = mid;
    }
    int right = lo2;
    int li = right - 1; if (li < 0) li = 0; if (li > TT - 1) li = TT - 1;
    int ri = right;     if (ri < 0) ri = 0; if (ri > TT - 1) ri = TT - 1;
    double pl = (double)runs[li] / tf, pr = (double)runs[ri] / tf;
    double denom = fabs(pr - pl); if (denom < 1e-6) denom = 1e-6;
    double alpha = (target - pl) / denom;
    if (alpha < 0.0) alpha = 0.0;
    if (alpha > 1.0) alpha = 1.0;
    if (right <= 0) alpha = 0.0;
    else if (right >= TT) alpha = 1.0;
    double fL[5], fR[5];
    for (int sdx = 0; sdx < 2; ++sdx){
      int i = sdx ? ri : li;
      double* f = sdx ? fR : fL;
      unsigned fl = flags[i];
      int j0 = i - 2; if (j0 < 0) j0 = 0;
      int j1 = i + 2; if (j1 > TT - 1) j1 = TT - 1;
      double ws = 0.0;
      for (int j = j0; j <= j1; ++j) ws += delta_s[j];
      f[0] = (fl & 1) ? 1.0 : 0.0;
      f[1] = ws / 5.0;
      f[2] = (fl & 4) ? 1.0 : 0.0;
      double u = (i == TT - 1) ? 1.0 : (double)i * (1.0 / 7999.0);
      f[3] = (double)runs[i] / tf - u;
      f[4] = (fl & 2) ? 1.0 : 0.0;
    }
    double om = 1.0 - alpha;
    float* tr = out + BB * 6 + ((size_t)b * NBINS + tid) * 5;
    #pragma unroll
    for (int f = 0; f < 5; ++f)
      tr[f] = (float)(fL[f] * om + fR[f] * alpha);
  }
}

extern "C" void kernel_launch(void* const* d_in, const int* in_sizes, int n_in,
                              void* d_out, int out_size, void* d_ws, size_t ws_size,
                              hipStream_t stream){
  const float* mel = (const float*)d_in[0];
  float* out = (float*)d_out;
  double* e_bt = (double*)d_ws;      // 512000 doubles = 4 MB

  hipLaunchKernelGGL(k_energy, dim3(8000), dim3(256), 0, stream, mel, e_bt);
  hipLaunchKernelGGL(k_row,    dim3(BB),   dim3(NT),  0, stream, e_bt, out);
}